// Round 1
// baseline (31152.182 us; speedup 1.0000x reference)
//
#include <hip/hip_runtime.h>
#include <math.h>

// Problem constants
constexpr int Bn  = 4;
constexpr int T   = 6;
constexpr int CIN = 3;
constexpr int CH  = 64;
constexpr int IMG = 128;
constexpr int HW  = IMG * IMG;          // 16384

// ---------------------------------------------------------------------------
// Transpose weights: src [Co=64, Ci, K, K] -> dst [Ci*K*K, 64]
// ---------------------------------------------------------------------------
__global__ void transpose_w(const float* __restrict__ src, float* __restrict__ dst,
                            int Ci, int K) {
    int n = 64 * Ci * K * K;
    int i = blockIdx.x * 256 + threadIdx.x;
    if (i >= n) return;
    int kk  = K * K;
    int cik = Ci * kk;
    int co  = i / cik;
    int rem = i - co * cik;            // ci*kk + ky*K + kx
    dst[rem * 64 + co] = src[i];
}

// ---------------------------------------------------------------------------
// Direct conv for one gate.
//   input = concat(in [B,CIN_IN,H,W] w/ batch stride in_bstride, hs [B,CH,H,W])
//   weights pre-transposed to [(CIN_IN+CH)*K*K, 64]
//   ACT: 0 = sigmoid, 1 = tanh
// Block: 256 threads = 32x32 pixel tile (thread: 1 col x 4 rows, stride 8).
// blockIdx.x: b*16 + tile (4x4 tiles of 32x32 over 128x128)
// blockIdx.y: group of 8 output channels
// ---------------------------------------------------------------------------
template<int K, int CIN_IN, int ACT>
__global__ __launch_bounds__(256)
void conv_gate(const float* __restrict__ in, long in_bstride,
               const float* __restrict__ hs,
               const float* __restrict__ wT,
               const float* __restrict__ bias,
               float* __restrict__ out)
{
    constexpr int PAD = K / 2;
    constexpr int KK  = K * K;
    constexpr int CI  = CIN_IN + CH;

    int pb   = blockIdx.x;
    int b    = pb >> 4;
    int tile = pb & 15;
    int ty   = (tile >> 2) * 32;
    int tx   = (tile & 3) * 32;
    int co0  = blockIdx.y * 8;

    int lane_c = threadIdx.x & 31;
    int lane_r = threadIdx.x >> 5;       // 0..7
    int col    = tx + lane_c;
    int row0   = ty + lane_r;            // rows: row0 + {0,8,16,24}

    float acc[4][8];
    #pragma unroll
    for (int p = 0; p < 4; ++p)
        #pragma unroll
        for (int j = 0; j < 8; ++j) acc[p][j] = 0.f;

    const float* inb = in + (long)b * in_bstride;
    const float* hb  = hs + (long)b * CH * HW;

    #pragma unroll 1
    for (int ci = 0; ci < CI; ++ci) {
        const float* sp = (ci < CIN_IN) ? (inb + (long)ci * HW)
                                        : (hb + (long)(ci - CIN_IN) * HW);
        #pragma unroll 1
        for (int ky = 0; ky < K; ++ky) {
            int  yy[4];
            bool yv[4];
            #pragma unroll
            for (int p = 0; p < 4; ++p) {
                yy[p] = row0 + p * 8 + ky - PAD;
                yv[p] = (yy[p] >= 0) && (yy[p] < IMG);
            }
            #pragma unroll
            for (int kx = 0; kx < K; ++kx) {
                int  xx = col + kx - PAD;
                bool xv = (xx >= 0) && (xx < IMG);
                const float4* w4 =
                    reinterpret_cast<const float4*>(wT + ((long)(ci * KK + ky * K + kx) * 64 + co0));
                float4 wa = w4[0];
                float4 wb = w4[1];
                #pragma unroll
                for (int p = 0; p < 4; ++p) {
                    float v = (yv[p] && xv) ? sp[yy[p] * IMG + xx] : 0.f;
                    acc[p][0] += v * wa.x;
                    acc[p][1] += v * wa.y;
                    acc[p][2] += v * wa.z;
                    acc[p][3] += v * wa.w;
                    acc[p][4] += v * wb.x;
                    acc[p][5] += v * wb.y;
                    acc[p][6] += v * wb.z;
                    acc[p][7] += v * wb.w;
                }
            }
        }
    }

    float* ob = out + (long)b * CH * HW;
    #pragma unroll
    for (int j = 0; j < 8; ++j) {
        float bv = bias[co0 + j];
        #pragma unroll
        for (int p = 0; p < 4; ++p) {
            float s = acc[p][j] + bv;
            float y;
            if (ACT == 0) y = 1.0f / (1.0f + __expf(-s));
            else          y = tanhf(s);
            ob[(long)(co0 + j) * HW + (long)(row0 + p * 8) * IMG + col] = y;
        }
    }
}

// ---------------------------------------------------------------------------
// hr = h * r   (elementwise, float4)
// ---------------------------------------------------------------------------
__global__ void mul_hr4(const float4* __restrict__ h, const float4* __restrict__ r,
                        float4* __restrict__ hr, int n4) {
    int i = blockIdx.x * 256 + threadIdx.x;
    if (i >= n4) return;
    float4 a = h[i], b = r[i];
    float4 c;
    c.x = a.x * b.x; c.y = a.y * b.y; c.z = a.z * b.z; c.w = a.w * b.w;
    hr[i] = c;
}

// ---------------------------------------------------------------------------
// h = h + u*(o - h)   (in-place, float4)
// ---------------------------------------------------------------------------
__global__ void pw_update4(float4* __restrict__ h, const float4* __restrict__ u,
                           const float4* __restrict__ o, int n4) {
    int i = blockIdx.x * 256 + threadIdx.x;
    if (i >= n4) return;
    float4 hv = h[i], uv = u[i], ov = o[i];
    hv.x = hv.x + uv.x * (ov.x - hv.x);
    hv.y = hv.y + uv.y * (ov.y - hv.y);
    hv.z = hv.z + uv.z * (ov.z - hv.z);
    hv.w = hv.w + uv.w * (ov.w - hv.w);
    h[i] = hv;
}

// ---------------------------------------------------------------------------
// 1x1 conv: x [24,3,H,W] -> out [24,64,H,W]
// thread computes 4 consecutive pixels of one (frame, co)
// ---------------------------------------------------------------------------
__global__ void conv1x1(const float* __restrict__ x, const float* __restrict__ w,
                        const float* __restrict__ bias, float* __restrict__ out) {
    int i  = blockIdx.x * 256 + threadIdx.x;   // 24*64*HW/4 = 6,291,456
    int q  = HW / 4;
    int p4 = i % q;
    int co = (i / q) & 63;
    int f  = i / (q * 64);
    const float4* xb = reinterpret_cast<const float4*>(x + (long)f * 3 * HW);
    float4 x0 = xb[p4];
    float4 x1 = xb[p4 + q];
    float4 x2 = xb[p4 + 2 * q];
    float w0 = w[co * 3], w1 = w[co * 3 + 1], w2 = w[co * 3 + 2];
    float bv = bias[co];
    float4 o;
    o.x = bv + x0.x * w0 + x1.x * w1 + x2.x * w2;
    o.y = bv + x0.y * w0 + x1.y * w1 + x2.y * w2;
    o.z = bv + x0.z * w0 + x1.z * w1 + x2.z * w2;
    o.w = bv + x0.w * w0 + x1.w * w1 + x2.w * w2;
    reinterpret_cast<float4*>(out)[i] = o;
}

// ---------------------------------------------------------------------------
extern "C" void kernel_launch(void* const* d_in, const int* in_sizes, int n_in,
                              void* d_out, int out_size, void* d_ws, size_t ws_size,
                              hipStream_t stream) {
    (void)in_sizes; (void)n_in; (void)out_size; (void)d_ws; (void)ws_size;

    const float* x    = (const float*)d_in[0];
    const float* w1   = (const float*)d_in[4];
    const float* b1   = (const float*)d_in[5];

    float* out = (float*)d_out;

    const long X0_N = 24L * CH * HW;         // 25,165,824 floats
    const long HN   = (long)Bn * CH * HW;    //  4,194,304 floats

    // hidden states live in their output slots
    float* H[3] = { out + X0_N, out + X0_N + HN, out + X0_N + 2 * HN };

    // scratch carved from the x0 region (written last)
    float* u_buf   = out;
    float* r_buf   = out + HN;
    float* o_buf   = out + 2 * HN;
    float* wt_base = out + 3 * HN;

    const long rows[3] = { (CIN + CH) * 9L, (CH + CH) * 25L, (CH + CH) * 49L }; // 603,3200,6272
    float *WTu[3], *WTr[3], *WTo[3];
    long off = 0;
    for (int L = 0; L < 3; ++L) {
        WTu[L] = wt_base + off; off += rows[L] * 64;
        WTr[L] = wt_base + off; off += rows[L] * 64;
        WTo[L] = wt_base + off; off += rows[L] * 64;
    }
    float* hr_buf = wt_base + off;   // off = 1,934,400 -> total < X0_N, fits

    // --- transpose all gate weights ---
    const int Ks[3]  = { 3, 5, 7 };
    const int Cis[3] = { CIN + CH, CH + CH, CH + CH };
    for (int L = 0; L < 3; ++L) {
        const float* wr = (const float*)d_in[6 + 6 * L];
        const float* wu = (const float*)d_in[8 + 6 * L];
        const float* wo = (const float*)d_in[10 + 6 * L];
        int n   = 64 * Cis[L] * Ks[L] * Ks[L];
        int nb  = (n + 255) / 256;
        transpose_w<<<nb, 256, 0, stream>>>(wu, WTu[L], Cis[L], Ks[L]);
        transpose_w<<<nb, 256, 0, stream>>>(wr, WTr[L], Cis[L], Ks[L]);
        transpose_w<<<nb, 256, 0, stream>>>(wo, WTo[L], Cis[L], Ks[L]);
    }

    // --- init hidden states from inputs ---
    for (int L = 0; L < 3; ++L)
        hipMemcpyAsync(H[L], d_in[1 + L], HN * sizeof(float),
                       hipMemcpyDeviceToDevice, stream);

    dim3 cgrid(64, 8, 1);
    const int n4  = (int)(HN / 4);
    const int nb4 = (n4 + 255) / 256;

    for (int t = 0; t < T; ++t) {
        for (int L = 0; L < 3; ++L) {
            const float* lin;
            long bstride;
            if (L == 0) { lin = x + (long)t * CIN * HW; bstride = (long)T * CIN * HW; }
            else        { lin = H[L - 1];               bstride = (long)CH * HW; }

            const float* bu = (const float*)d_in[9 + 6 * L];
            const float* br = (const float*)d_in[7 + 6 * L];
            const float* bo = (const float*)d_in[11 + 6 * L];

            if (L == 0) {
                conv_gate<3, CIN, 0><<<cgrid, 256, 0, stream>>>(lin, bstride, H[0], WTu[0], bu, u_buf);
                conv_gate<3, CIN, 0><<<cgrid, 256, 0, stream>>>(lin, bstride, H[0], WTr[0], br, r_buf);
                mul_hr4<<<nb4, 256, 0, stream>>>((const float4*)H[0], (const float4*)r_buf, (float4*)hr_buf, n4);
                conv_gate<3, CIN, 1><<<cgrid, 256, 0, stream>>>(lin, bstride, hr_buf, WTo[0], bo, o_buf);
                pw_update4<<<nb4, 256, 0, stream>>>((float4*)H[0], (const float4*)u_buf, (const float4*)o_buf, n4);
            } else if (L == 1) {
                conv_gate<5, CH, 0><<<cgrid, 256, 0, stream>>>(lin, bstride, H[1], WTu[1], bu, u_buf);
                conv_gate<5, CH, 0><<<cgrid, 256, 0, stream>>>(lin, bstride, H[1], WTr[1], br, r_buf);
                mul_hr4<<<nb4, 256, 0, stream>>>((const float4*)H[1], (const float4*)r_buf, (float4*)hr_buf, n4);
                conv_gate<5, CH, 1><<<cgrid, 256, 0, stream>>>(lin, bstride, hr_buf, WTo[1], bo, o_buf);
                pw_update4<<<nb4, 256, 0, stream>>>((float4*)H[1], (const float4*)u_buf, (const float4*)o_buf, n4);
            } else {
                conv_gate<7, CH, 0><<<cgrid, 256, 0, stream>>>(lin, bstride, H[2], WTu[2], bu, u_buf);
                conv_gate<7, CH, 0><<<cgrid, 256, 0, stream>>>(lin, bstride, H[2], WTr[2], br, r_buf);
                mul_hr4<<<nb4, 256, 0, stream>>>((const float4*)H[2], (const float4*)r_buf, (float4*)hr_buf, n4);
                conv_gate<7, CH, 1><<<cgrid, 256, 0, stream>>>(lin, bstride, hr_buf, WTo[2], bo, o_buf);
                pw_update4<<<nb4, 256, 0, stream>>>((float4*)H[2], (const float4*)u_buf, (const float4*)o_buf, n4);
            }
        }
    }

    // x0 projection last — overwrites the scratch region with the real output
    conv1x1<<<(24 * CH * HW / 4 + 255) / 256, 256, 0, stream>>>(x, w1, b1, out);
}

// Round 2
// 6113.302 us; speedup vs baseline: 5.0958x; 5.0958x over previous
//
#include <hip/hip_runtime.h>
#include <math.h>

// Problem constants
constexpr int Bn  = 4;
constexpr int T   = 6;
constexpr int CIN = 3;
constexpr int CH  = 64;
constexpr int IMG = 128;
constexpr int HW  = IMG * IMG;          // 16384

// Channels-last padded input buffer geometry: [b][136][136][128] bf16 (ushort)
constexpr int CLY = 136;                // 128 + 2*4 halo
constexpr int CIP = 128;                // padded channel count (uniform all layers)
constexpr long CL_USHORTS = 4L * CLY * CLY * CIP;   // 9,469,952

typedef short bf16x8 __attribute__((ext_vector_type(8)));
typedef float f32x4  __attribute__((ext_vector_type(4)));

__device__ __forceinline__ unsigned short f2bf(float f) {
    union { float f; unsigned int u; } v; v.f = f;
    unsigned int u = v.u;
    unsigned int r = (u + 0x7FFFu + ((u >> 16) & 1u)) >> 16;   // RNE
    return (unsigned short)r;
}

// ---------------------------------------------------------------------------
// Weight transform: OIHW fp32 -> MFMA A-fragment layout bf16.
// dst frag index = ((kyx*NCIC + cic)*NCOC + coc), frag = 64 lanes x 8 bf16
//   element: co = coc*16 + (lane&15);  ci = cic*32 + (lane>>4)*8 + j
// For fused u|r convs: co<64 -> wA (u), co>=64 -> wB (r).
// ---------------------------------------------------------------------------
__global__ void xform_w(const float* __restrict__ wA, const float* __restrict__ wB,
                        unsigned short* __restrict__ dst,
                        int K, int CI, int NCIC, int NCOC) {
    int idx   = blockIdx.x * 256 + threadIdx.x;
    int total = K * K * NCIC * NCOC * 64;
    if (idx >= total) return;
    int lane = idx & 63;
    int rest = idx >> 6;
    int coc  = rest % NCOC; rest /= NCOC;
    int cic  = rest % NCIC; rest /= NCIC;
    int kyx  = rest;
    int co_g = coc * 16 + (lane & 15);
    const float* w = (co_g < 64) ? wA : wB;
    int co = co_g & 63;
    union { unsigned short u[8]; uint4 q; } t;
    #pragma unroll
    for (int j = 0; j < 8; ++j) {
        int ci  = cic * 32 + (lane >> 4) * 8 + j;
        float f = (ci < CI) ? w[(long)(co * CI + ci) * K * K + kyx] : 0.f;
        t.u[j] = f2bf(f);
    }
    *(uint4*)(dst + (long)idx * 8) = t.q;
}

// ---------------------------------------------------------------------------
// Build channels-last bf16 input: dst[b][4+y][4+x][ci] = concat(src0, h (*r))
//   ci < C0            : src0 channel ci       (batch stride bs0)
//   C0 <= ci < C0+64   : h channel (ci-C0), optionally multiplied by rmul
//   else               : 0
// One thread writes 8 channels (16B) of one pixel. NG = number of 8-ch groups.
// ---------------------------------------------------------------------------
__global__ void build_cl(const float* __restrict__ src0, int bs0, int C0,
                         const float* __restrict__ h, const float* __restrict__ rmul,
                         unsigned short* __restrict__ dst, int NG) {
    int i    = blockIdx.x * 256 + threadIdx.x;
    int px   = i & 16383;
    int rest = i >> 14;
    int g    = rest % NG;
    int b    = rest / NG;
    int y    = px >> 7, x = px & 127;
    union { unsigned short u[8]; uint4 q; } t;
    #pragma unroll
    for (int j = 0; j < 8; ++j) {
        int ci  = g * 8 + j;
        float f = 0.f;
        if (ci < C0) {
            f = src0[(long)b * bs0 + (long)ci * HW + px];
        } else if (ci < C0 + 64) {
            int c = ci - C0;
            f = h[(long)(b * 64 + c) * HW + px];
            if (rmul) f *= rmul[(long)(b * 64 + c) * HW + px];
        }
        t.u[j] = f2bf(f);
    }
    long off = (((long)b * CLY + 4 + y) * CLY + 4 + x) * CIP + g * 8;
    *(uint4*)(dst + off) = t.q;
}

// ---------------------------------------------------------------------------
// Implicit-GEMM conv via mfma_f32_16x16x32_bf16.
//   Wave tile: 32 px (one row segment) x 64 co. Block = 4 waves.
//   COGS=1: CO=64 (o-conv), 4 px-subtiles per block.
//   COGS=2: CO=128 (fused u|r), 2 px-subtiles x 2 co-groups per block.
// MODE 0: sigmoid -> (cog? out_r : out_u)
// MODE 1: o = tanh; h = h + u*(o - h) fused update (in-place on hstate)
// ---------------------------------------------------------------------------
template<int K, int NCIC, int COGS, int MODE>
__global__ __launch_bounds__(256)
void conv_mfma(const unsigned short* __restrict__ cl,
               const unsigned short* __restrict__ wt,
               const float* __restrict__ bias_u, const float* __restrict__ bias_r,
               float* __restrict__ out_u, float* __restrict__ out_r,
               float* __restrict__ hstate, const float* __restrict__ ubuf)
{
    constexpr int NCOC = COGS * 4;
    constexpr int HOFF = 4 - K / 2;

    int w    = threadIdx.x >> 6;
    int lane = threadIdx.x & 63;
    int gw   = blockIdx.x * 4 + w;
    int cog  = (COGS == 2) ? (gw & 1) : 0;
    int pt   = (COGS == 2) ? (gw >> 1) : gw;
    int b    = pt >> 9;
    int rem  = pt & 511;
    int y    = rem >> 2;
    int x0   = (rem & 3) << 5;
    int n    = lane & 15;
    int kg   = lane >> 4;

    f32x4 acc[4][2];
    #pragma unroll
    for (int c = 0; c < 4; ++c)
        #pragma unroll
        for (int s = 0; s < 2; ++s)
            acc[c][s] = (f32x4){0.f, 0.f, 0.f, 0.f};

    const unsigned short* clb =
        cl + ((long)(b * CLY + HOFF + y) * CLY + HOFF + x0 + n) * CIP + kg * 8;
    const unsigned short* wtc = wt + (long)(cog * 4) * 512 + lane * 8;

    #pragma unroll 2
    for (int kyx = 0; kyx < K * K; ++kyx) {
        int ky = kyx / K;
        int kx = kyx - ky * K;
        const unsigned short* bp = clb + (ky * CLY + kx) * CIP;
        const unsigned short* wp = wtc + (long)kyx * NCIC * NCOC * 512;
        #pragma unroll
        for (int cic = 0; cic < NCIC; ++cic) {
            bf16x8 b0 = *(const bf16x8*)(bp + cic * 32);
            bf16x8 b1 = *(const bf16x8*)(bp + 16 * CIP + cic * 32);
            #pragma unroll
            for (int coc = 0; coc < 4; ++coc) {
                bf16x8 a = *(const bf16x8*)(wp + (long)(cic * NCOC + coc) * 512);
                acc[coc][0] = __builtin_amdgcn_mfma_f32_16x16x32_bf16(a, b0, acc[coc][0], 0, 0, 0);
                acc[coc][1] = __builtin_amdgcn_mfma_f32_16x16x32_bf16(a, b1, acc[coc][1], 0, 0, 0);
            }
        }
    }

    const float* bias = (MODE == 0) ? (cog ? bias_r : bias_u) : bias_u;
    float* dst        = (MODE == 0) ? (cog ? out_r : out_u)   : hstate;

    #pragma unroll
    for (int coc = 0; coc < 4; ++coc) {
        int co_l = coc * 16 + kg * 4;
        #pragma unroll
        for (int s = 0; s < 2; ++s) {
            int x = x0 + n + s * 16;
            f32x4 v = acc[coc][s];
            #pragma unroll
            for (int r = 0; r < 4; ++r) {
                int co    = co_l + r;
                float val = v[r] + bias[co];
                long idx  = (long)(b * 64 + co) * HW + y * IMG + x;
                if (MODE == 0) {
                    dst[idx] = 1.f / (1.f + __expf(-val));       // sigmoid
                } else {
                    float o  = 1.f - 2.f / (1.f + __expf(2.f * val));  // tanh, stable
                    float hv = hstate[idx];
                    float uv = ubuf[idx];
                    dst[idx] = hv + uv * (o - hv);
                }
            }
        }
    }
}

// ---------------------------------------------------------------------------
// 1x1 conv: x [24,3,H,W] -> out [24,64,H,W]  (fp32, memory-bound)
// ---------------------------------------------------------------------------
__global__ void conv1x1(const float* __restrict__ x, const float* __restrict__ w,
                        const float* __restrict__ bias, float* __restrict__ out) {
    int i  = blockIdx.x * 256 + threadIdx.x;
    int q  = HW / 4;
    int p4 = i % q;
    int co = (i / q) & 63;
    int f  = i / (q * 64);
    const float4* xb = reinterpret_cast<const float4*>(x + (long)f * 3 * HW);
    float4 x0 = xb[p4];
    float4 x1 = xb[p4 + q];
    float4 x2 = xb[p4 + 2 * q];
    float w0 = w[co * 3], w1 = w[co * 3 + 1], w2 = w[co * 3 + 2];
    float bv = bias[co];
    float4 o;
    o.x = bv + x0.x * w0 + x1.x * w1 + x2.x * w2;
    o.y = bv + x0.y * w0 + x1.y * w1 + x2.y * w2;
    o.z = bv + x0.z * w0 + x1.z * w1 + x2.z * w2;
    o.w = bv + x0.w * w0 + x1.w * w1 + x2.w * w2;
    reinterpret_cast<float4*>(out)[i] = o;
}

// ---------------------------------------------------------------------------
extern "C" void kernel_launch(void* const* d_in, const int* in_sizes, int n_in,
                              void* d_out, int out_size, void* d_ws, size_t ws_size,
                              hipStream_t stream) {
    (void)in_sizes; (void)n_in; (void)out_size; (void)d_ws; (void)ws_size;

    const float* x  = (const float*)d_in[0];
    const float* w1 = (const float*)d_in[4];
    const float* b1 = (const float*)d_in[5];

    float* out = (float*)d_out;

    const long X0_N = 24L * CH * HW;         // 25,165,824 floats (x0 region)
    const long HN   = (long)Bn * CH * HW;    //  4,194,304 floats

    // hidden states live in their final output slots
    float* H[3] = { out + X0_N, out + X0_N + HN, out + X0_N + 2 * HN };

    // scratch carved from the x0 region (overwritten by conv1x1 at the end)
    float* u_buf = out;                       // 4,194,304 f
    float* r_buf = out + HN;                  // 4,194,304 f
    unsigned short* cl = (unsigned short*)(out + 2 * HN);   // 9,469,952 us = 4,734,976 f
    unsigned short* wt = (unsigned short*)(out + 2 * HN + 4734976);

    // wt sub-offsets (ushorts)
    const long WT_UR[3] = { 0,       165888, 780288  };
    const long WT_O [3] = { 110592,  575488, 1583104 };
    // sizes: L0 ur 110592, L0 o 55296, L1 ur 409600, L1 o 204800,
    //        L2 ur 802816, L2 o 401408 -> total 1,984,512 us = 992,256 f
    // total scratch = 8,388,608 + 4,734,976 + 992,256 = 14,115,840 < 25,165,824 OK

    const int Ks[3]   = { 3, 5, 7 };
    const int CIs[3]  = { CIN + CH, 2 * CH, 2 * CH };   // 67, 128, 128
    const int NCIC[3] = { 3, 4, 4 };
    const int NGs[3]  = { 9, 16, 16 };                  // ceil((C0+64)/8)

    // zero the CL buffer once (halo must be zero; interiors rebuilt per cell)
    hipMemsetAsync(cl, 0, CL_USHORTS * sizeof(unsigned short), stream);

    // weight transforms
    for (int L = 0; L < 3; ++L) {
        const float* wr = (const float*)d_in[6 + 6 * L];
        const float* wu = (const float*)d_in[8 + 6 * L];
        const float* wo = (const float*)d_in[10 + 6 * L];
        int K = Ks[L], CI = CIs[L], NC = NCIC[L];
        int tot_ur = K * K * NC * 8 * 64;
        int tot_o  = K * K * NC * 4 * 64;
        xform_w<<<(tot_ur + 255) / 256, 256, 0, stream>>>(wu, wr, wt + WT_UR[L], K, CI, NC, 8);
        xform_w<<<(tot_o  + 255) / 256, 256, 0, stream>>>(wo, wo, wt + WT_O[L],  K, CI, NC, 4);
    }

    // init hidden states
    for (int L = 0; L < 3; ++L)
        hipMemcpyAsync(H[L], d_in[1 + L], HN * sizeof(float),
                       hipMemcpyDeviceToDevice, stream);

    for (int t = 0; t < T; ++t) {
        for (int L = 0; L < 3; ++L) {
            const float* src0;
            int bs0, C0 = (L == 0) ? CIN : CH;
            if (L == 0) { src0 = x + (long)t * CIN * HW; bs0 = T * CIN * HW; }
            else        { src0 = H[L - 1];               bs0 = CH * HW; }

            const float* br = (const float*)d_in[7 + 6 * L];
            const float* bu = (const float*)d_in[9 + 6 * L];
            const float* bo = (const float*)d_in[11 + 6 * L];

            int NG       = NGs[L];
            int nb_build = 4 * NG * 64;   // (4*16384*NG)/256

            // 1) stacked = concat(in, h)  -> CL
            build_cl<<<nb_build, 256, 0, stream>>>(src0, bs0, C0, H[L], nullptr, cl, NG);
            // 2) fused u|r conv (CO=128)
            if (L == 0)
                conv_mfma<3, 3, 2, 0><<<1024, 256, 0, stream>>>(cl, wt + WT_UR[0], bu, br, u_buf, r_buf, nullptr, nullptr);
            else if (L == 1)
                conv_mfma<5, 4, 2, 0><<<1024, 256, 0, stream>>>(cl, wt + WT_UR[1], bu, br, u_buf, r_buf, nullptr, nullptr);
            else
                conv_mfma<7, 4, 2, 0><<<1024, 256, 0, stream>>>(cl, wt + WT_UR[2], bu, br, u_buf, r_buf, nullptr, nullptr);
            // 3) concat(in, h*r) -> CL
            build_cl<<<nb_build, 256, 0, stream>>>(src0, bs0, C0, H[L], r_buf, cl, NG);
            // 4) o-conv + fused GRU update (CO=64), writes H[L] in place
            if (L == 0)
                conv_mfma<3, 3, 1, 1><<<512, 256, 0, stream>>>(cl, wt + WT_O[0], bo, bo, nullptr, nullptr, H[0], u_buf);
            else if (L == 1)
                conv_mfma<5, 4, 1, 1><<<512, 256, 0, stream>>>(cl, wt + WT_O[1], bo, bo, nullptr, nullptr, H[1], u_buf);
            else
                conv_mfma<7, 4, 1, 1><<<512, 256, 0, stream>>>(cl, wt + WT_O[2], bo, bo, nullptr, nullptr, H[2], u_buf);
        }
    }

    // x0 projection last — overwrites the scratch region with the real output
    conv1x1<<<(24 * CH * HW / 4 + 255) / 256, 256, 0, stream>>>(x, w1, b1, out);
}

// Round 3
// 4321.066 us; speedup vs baseline: 7.2094x; 1.4148x over previous
//
#include <hip/hip_runtime.h>
#include <math.h>

// Problem constants
constexpr int Bn  = 4;
constexpr int T   = 6;
constexpr int CIN = 3;
constexpr int CH  = 64;
constexpr int IMG = 128;
constexpr int HW  = IMG * IMG;          // 16384

// Channels-last padded input buffer geometry: [b][136][136][128] bf16 (ushort)
constexpr int CLY = 136;                // 128 + 2*4 halo
constexpr int CIP = 128;                // padded channel count (uniform all layers)
constexpr long CL_USHORTS = 4L * CLY * CLY * CIP;   // 9,469,952

typedef short bf16x8 __attribute__((ext_vector_type(8)));
typedef float f32x4  __attribute__((ext_vector_type(4)));

__device__ __forceinline__ unsigned short f2bf(float f) {
    union { float f; unsigned int u; } v; v.f = f;
    unsigned int u = v.u;
    unsigned int r = (u + 0x7FFFu + ((u >> 16) & 1u)) >> 16;   // RNE
    return (unsigned short)r;
}

// ---------------------------------------------------------------------------
// Weight transform: OIHW fp32 -> MFMA A-fragment layout bf16.
// dst frag index = ((kyx*NCIC + cic)*NCOC + coc), frag = 64 lanes x 8 bf16
//   element: co = coc*16 + (lane&15);  ci = cic*32 + (lane>>4)*8 + j
// For fused u|r convs: co<64 -> wA (u), co>=64 -> wB (r).
// ---------------------------------------------------------------------------
__global__ void xform_w(const float* __restrict__ wA, const float* __restrict__ wB,
                        unsigned short* __restrict__ dst,
                        int K, int CI, int NCIC, int NCOC) {
    int idx   = blockIdx.x * 256 + threadIdx.x;
    int total = K * K * NCIC * NCOC * 64;
    if (idx >= total) return;
    int lane = idx & 63;
    int rest = idx >> 6;
    int coc  = rest % NCOC; rest /= NCOC;
    int cic  = rest % NCIC; rest /= NCIC;
    int kyx  = rest;
    int co_g = coc * 16 + (lane & 15);
    const float* w = (co_g < 64) ? wA : wB;
    int co = co_g & 63;
    union { unsigned short u[8]; uint4 q; } t;
    #pragma unroll
    for (int j = 0; j < 8; ++j) {
        int ci  = cic * 32 + (lane >> 4) * 8 + j;
        float f = (ci < CI) ? w[(long)(co * CI + ci) * K * K + kyx] : 0.f;
        t.u[j] = f2bf(f);
    }
    *(uint4*)(dst + (long)idx * 8) = t.q;
}

// ---------------------------------------------------------------------------
// Build channels-last bf16 input: dst[b][4+y][4+x][ci] = concat(src0, h (*r))
//   ci < C0            : src0 channel ci       (batch stride bs0)
//   C0 <= ci < C0+64   : h channel (ci-C0), optionally multiplied by rmul
//   else               : 0
// One thread writes 8 channels (16B) of one pixel.
// Writes channel groups GS .. GS+NGE-1.
// ---------------------------------------------------------------------------
__global__ void build_cl(const float* __restrict__ src0, int bs0, int C0,
                         const float* __restrict__ h, const float* __restrict__ rmul,
                         unsigned short* __restrict__ dst, int GS, int NGE) {
    int i    = blockIdx.x * 256 + threadIdx.x;
    int px   = i & 16383;
    int rest = i >> 14;
    int g    = GS + rest % NGE;
    int b    = rest / NGE;
    int y    = px >> 7, x = px & 127;
    union { unsigned short u[8]; uint4 q; } t;
    #pragma unroll
    for (int j = 0; j < 8; ++j) {
        int ci  = g * 8 + j;
        float f = 0.f;
        if (ci < C0) {
            f = src0[(long)b * bs0 + (long)ci * HW + px];
        } else if (ci < C0 + 64) {
            int c = ci - C0;
            f = h[(long)(b * 64 + c) * HW + px];
            if (rmul) f *= rmul[(long)(b * 64 + c) * HW + px];
        }
        t.u[j] = f2bf(f);
    }
    long off = (((long)b * CLY + 4 + y) * CLY + 4 + x) * CIP + g * 8;
    *(uint4*)(dst + off) = t.q;
}

// ---------------------------------------------------------------------------
// Implicit-GEMM conv via mfma_f32_16x16x32_bf16.
//   Wave tile: 64 px (one row segment) x 64 co -> acc 16 x f32x4.
//   Block = 4 waves (consecutive px tiles, SAME cog -> shared weight stream).
//   blockIdx.y = cog (0 for CO=64 o-conv; 0/1 for fused u|r CO=128).
// MODE 0: sigmoid -> (cog? out_r : out_u)
// MODE 1: o = tanh; h = h + u*(o - h) fused update (in-place on hstate)
// ---------------------------------------------------------------------------
template<int K, int NCIC, int COGS, int MODE>
__global__ __launch_bounds__(256)
void conv_mfma(const unsigned short* __restrict__ cl,
               const unsigned short* __restrict__ wt,
               const float* __restrict__ bias_u, const float* __restrict__ bias_r,
               float* __restrict__ out_u, float* __restrict__ out_r,
               float* __restrict__ hstate, const float* __restrict__ ubuf)
{
    constexpr int NCOC = COGS * 4;
    constexpr int HOFF = 4 - K / 2;

    int w    = threadIdx.x >> 6;
    int lane = threadIdx.x & 63;
    int cog  = blockIdx.y;
    int pt   = blockIdx.x * 4 + w;       // 0 .. 4*128*2-1
    int b    = pt >> 8;
    int rem  = pt & 255;
    int y    = rem >> 1;
    int x0   = (rem & 1) << 6;
    int n    = lane & 15;
    int kg   = lane >> 4;

    f32x4 acc[4][4];
    #pragma unroll
    for (int c = 0; c < 4; ++c)
        #pragma unroll
        for (int s = 0; s < 4; ++s)
            acc[c][s] = (f32x4){0.f, 0.f, 0.f, 0.f};

    const unsigned short* clb =
        cl + ((long)(b * CLY + HOFF + y) * CLY + HOFF + x0 + n) * CIP + kg * 8;
    const unsigned short* wtc = wt + (long)(cog * 4) * 512 + lane * 8;

    #pragma unroll 1
    for (int kyx = 0; kyx < K * K; ++kyx) {
        int ky = kyx / K;
        int kx = kyx - ky * K;
        const unsigned short* bp = clb + (ky * CLY + kx) * CIP;
        const unsigned short* wp = wtc + (long)kyx * NCIC * NCOC * 512;
        #pragma unroll
        for (int cic = 0; cic < NCIC; ++cic) {
            bf16x8 bfr[4], afr[4];
            #pragma unroll
            for (int s = 0; s < 4; ++s)
                bfr[s] = *(const bf16x8*)(bp + s * 16 * CIP + cic * 32);
            #pragma unroll
            for (int c = 0; c < 4; ++c)
                afr[c] = *(const bf16x8*)(wp + (long)(cic * NCOC + c) * 512);
            #pragma unroll
            for (int c = 0; c < 4; ++c)
                #pragma unroll
                for (int s = 0; s < 4; ++s)
                    acc[c][s] = __builtin_amdgcn_mfma_f32_16x16x32_bf16(afr[c], bfr[s], acc[c][s], 0, 0, 0);
        }
    }

    const float* bias = (MODE == 0) ? (cog ? bias_r : bias_u) : bias_u;
    float* dst        = (MODE == 0) ? (cog ? out_r : out_u)   : hstate;

    #pragma unroll
    for (int coc = 0; coc < 4; ++coc) {
        int co_l = coc * 16 + kg * 4;
        #pragma unroll
        for (int s = 0; s < 4; ++s) {
            int x = x0 + s * 16 + n;
            f32x4 v = acc[coc][s];
            #pragma unroll
            for (int r = 0; r < 4; ++r) {
                int co    = co_l + r;
                float val = v[r] + bias[co];
                long idx  = (long)(b * 64 + co) * HW + y * IMG + x;
                if (MODE == 0) {
                    dst[idx] = 1.f / (1.f + __expf(-val));       // sigmoid
                } else {
                    float o  = 1.f - 2.f / (1.f + __expf(2.f * val));  // tanh, stable
                    float hv = hstate[idx];
                    float uv = ubuf[idx];
                    dst[idx] = hv + uv * (o - hv);
                }
            }
        }
    }
}

// ---------------------------------------------------------------------------
// 1x1 conv: x [24,3,H,W] -> out [24,64,H,W]  (fp32, memory-bound)
// ---------------------------------------------------------------------------
__global__ void conv1x1(const float* __restrict__ x, const float* __restrict__ w,
                        const float* __restrict__ bias, float* __restrict__ out) {
    int i  = blockIdx.x * 256 + threadIdx.x;
    int q  = HW / 4;
    int p4 = i % q;
    int co = (i / q) & 63;
    int f  = i / (q * 64);
    const float4* xb = reinterpret_cast<const float4*>(x + (long)f * 3 * HW);
    float4 x0 = xb[p4];
    float4 x1 = xb[p4 + q];
    float4 x2 = xb[p4 + 2 * q];
    float w0 = w[co * 3], w1 = w[co * 3 + 1], w2 = w[co * 3 + 2];
    float bv = bias[co];
    float4 o;
    o.x = bv + x0.x * w0 + x1.x * w1 + x2.x * w2;
    o.y = bv + x0.y * w0 + x1.y * w1 + x2.y * w2;
    o.z = bv + x0.z * w0 + x1.z * w1 + x2.z * w2;
    o.w = bv + x0.w * w0 + x1.w * w1 + x2.w * w2;
    reinterpret_cast<float4*>(out)[i] = o;
}

// ---------------------------------------------------------------------------
extern "C" void kernel_launch(void* const* d_in, const int* in_sizes, int n_in,
                              void* d_out, int out_size, void* d_ws, size_t ws_size,
                              hipStream_t stream) {
    (void)in_sizes; (void)n_in; (void)out_size; (void)d_ws; (void)ws_size;

    const float* x  = (const float*)d_in[0];
    const float* w1 = (const float*)d_in[4];
    const float* b1 = (const float*)d_in[5];

    float* out = (float*)d_out;

    const long X0_N = 24L * CH * HW;         // 25,165,824 floats (x0 region)
    const long HN   = (long)Bn * CH * HW;    //  4,194,304 floats

    // hidden states live in their final output slots
    float* H[3] = { out + X0_N, out + X0_N + HN, out + X0_N + 2 * HN };

    // scratch carved from the x0 region (overwritten by conv1x1 at the end)
    float* u_buf = out;                       // 4,194,304 f
    float* r_buf = out + HN;                  // 4,194,304 f
    unsigned short* cl = (unsigned short*)(out + 2 * HN);   // 9,469,952 us = 4,734,976 f
    unsigned short* wt = (unsigned short*)(out + 2 * HN + 4734976);

    // wt sub-offsets (ushorts)
    const long WT_UR[3] = { 0,       165888, 780288  };
    const long WT_O [3] = { 110592,  575488, 1583104 };
    // total scratch = 8,388,608 + 4,734,976 + 992,256 = 14,115,840 < 25,165,824 OK

    const int Ks[3]   = { 3, 5, 7 };
    const int CIs[3]  = { CIN + CH, 2 * CH, 2 * CH };   // 67, 128, 128
    const int NCIC[3] = { 3, 4, 4 };
    const int NGs[3]  = { 9, 16, 16 };                  // ceil((C0+64)/8)

    // zero the CL buffer once (halo must be zero; interiors rebuilt per cell)
    hipMemsetAsync(cl, 0, CL_USHORTS * sizeof(unsigned short), stream);

    // weight transforms
    for (int L = 0; L < 3; ++L) {
        const float* wr = (const float*)d_in[6 + 6 * L];
        const float* wu = (const float*)d_in[8 + 6 * L];
        const float* wo = (const float*)d_in[10 + 6 * L];
        int K = Ks[L], CI = CIs[L], NC = NCIC[L];
        int tot_ur = K * K * NC * 8 * 64;
        int tot_o  = K * K * NC * 4 * 64;
        xform_w<<<(tot_ur + 255) / 256, 256, 0, stream>>>(wu, wr, wt + WT_UR[L], K, CI, NC, 8);
        xform_w<<<(tot_o  + 255) / 256, 256, 0, stream>>>(wo, wo, wt + WT_O[L],  K, CI, NC, 4);
    }

    // init hidden states
    for (int L = 0; L < 3; ++L)
        hipMemcpyAsync(H[L], d_in[1 + L], HN * sizeof(float),
                       hipMemcpyDeviceToDevice, stream);

    for (int t = 0; t < T; ++t) {
        for (int L = 0; L < 3; ++L) {
            const float* src0;
            int bs0, C0 = (L == 0) ? CIN : CH;
            if (L == 0) { src0 = x + (long)t * CIN * HW; bs0 = T * CIN * HW; }
            else        { src0 = H[L - 1];               bs0 = CH * HW; }

            const float* br = (const float*)d_in[7 + 6 * L];
            const float* bu = (const float*)d_in[9 + 6 * L];
            const float* bo = (const float*)d_in[11 + 6 * L];

            int NG  = NGs[L];
            // build #2 only needs the h-channel groups when C0 is 8-aligned
            int GS2 = (L == 0) ? 0 : 8;
            int NG2 = (L == 0) ? 9 : 8;

            // 1) stacked = concat(in, h)  -> CL
            build_cl<<<4 * NG * 64, 256, 0, stream>>>(src0, bs0, C0, H[L], nullptr, cl, 0, NG);
            // 2) fused u|r conv (CO=128)
            if (L == 0)
                conv_mfma<3, 3, 2, 0><<<dim3(256, 2), 256, 0, stream>>>(cl, wt + WT_UR[0], bu, br, u_buf, r_buf, nullptr, nullptr);
            else if (L == 1)
                conv_mfma<5, 4, 2, 0><<<dim3(256, 2), 256, 0, stream>>>(cl, wt + WT_UR[1], bu, br, u_buf, r_buf, nullptr, nullptr);
            else
                conv_mfma<7, 4, 2, 0><<<dim3(256, 2), 256, 0, stream>>>(cl, wt + WT_UR[2], bu, br, u_buf, r_buf, nullptr, nullptr);
            // 3) concat(in, h*r) -> CL (only h-groups where possible)
            build_cl<<<4 * NG2 * 64, 256, 0, stream>>>(src0, bs0, C0, H[L], r_buf, cl, GS2, NG2);
            // 4) o-conv + fused GRU update (CO=64), writes H[L] in place
            if (L == 0)
                conv_mfma<3, 3, 1, 1><<<dim3(256, 1), 256, 0, stream>>>(cl, wt + WT_O[0], bo, bo, nullptr, nullptr, H[0], u_buf);
            else if (L == 1)
                conv_mfma<5, 4, 1, 1><<<dim3(256, 1), 256, 0, stream>>>(cl, wt + WT_O[1], bo, bo, nullptr, nullptr, H[1], u_buf);
            else
                conv_mfma<7, 4, 1, 1><<<dim3(256, 1), 256, 0, stream>>>(cl, wt + WT_O[2], bo, bo, nullptr, nullptr, H[2], u_buf);
        }
    }

    // x0 projection last — overwrites the scratch region with the real output
    conv1x1<<<(24 * CH * HW / 4 + 255) / 256, 256, 0, stream>>>(x, w1, b1, out);
}